// Round 1
// baseline (354.028 us; speedup 1.0000x reference)
//
#include <hip/hip_runtime.h>

typedef unsigned short u16;
typedef short bf16x8 __attribute__((ext_vector_type(8)));
typedef float f32x4 __attribute__((ext_vector_type(4)));

__device__ __forceinline__ u16 f2b(float f) {
    union { float f; unsigned int u; } cv; cv.f = f;
    unsigned int u = cv.u;
    u += 0x7fffu + ((u >> 16) & 1u);
    return (u16)(u >> 16);
}

// ---------------- prep: weight transpose + bf16 convert ----------------
// wqkvT[n][k] = w_{which}[k][n&511]  (n in [0,1536), k in [0,512))
// woT[n][k]   = wo[k][n]             (n,k in [0,512))
__global__ void prep_kernel(const float* __restrict__ wq, const float* __restrict__ wk,
                            const float* __restrict__ wv, const float* __restrict__ wo,
                            const float* __restrict__ bq, const float* __restrict__ bk,
                            const float* __restrict__ bv,
                            u16* __restrict__ wqkvT, u16* __restrict__ woT,
                            float* __restrict__ biasq) {
    int idx = blockIdx.x * 256 + threadIdx.x;
    const int N1 = 512 * 1536;
    const int N2 = 512 * 512;
    if (idx < N1) {
        int k = idx / 1536, n = idx % 1536;          // coalesced read along n
        int which = n >> 9, nn = n & 511;
        const float* w = (which == 0) ? wq : (which == 1) ? wk : wv;
        wqkvT[n * 512 + k] = f2b(w[k * 512 + nn]);
    } else if (idx < N1 + N2) {
        int j = idx - N1;
        int k = j / 512, n = j % 512;
        woT[n * 512 + k] = f2b(wo[k * 512 + n]);
    } else if (idx < N1 + N2 + 1536) {
        int n = idx - N1 - N2;
        biasq[n] = (n < 512) ? bq[n] : (n < 1024) ? bk[n - 512] : bv[n - 1024];
    }
}

// ---------------- QKV GEMM: M=32768 N=1536 K=512 ----------------
// A = x fp32 (convert to bf16 at stage), B^T = wqkvT bf16.
// Epilogue scatters into windowed Q/K ([win][h][t][d]) and V^T ([win][h][d][t]).
__global__ __launch_bounds__(256) void qkv_gemm(const float* __restrict__ x,
        const u16* __restrict__ wqkvT, const float* __restrict__ biasq,
        u16* __restrict__ qws, u16* __restrict__ kws, u16* __restrict__ vws) {
    __shared__ u16 As[128 * 40];   // 128 rows x 32 (pad to 40)
    __shared__ u16 Bs[128 * 40];
    const int tid = threadIdx.x;
    const int lane = tid & 63, wid = tid >> 6;
    const int wr = wid >> 1, wc = wid & 1;
    const int m = lane & 15, qd = lane >> 4;
    const int rowBase = blockIdx.y * 128;
    const int colBase = blockIdx.x * 128;

    f32x4 acc[4][4];
#pragma unroll
    for (int i = 0; i < 4; ++i)
#pragma unroll
        for (int j = 0; j < 4; ++j) acc[i][j] = (f32x4){0.f, 0.f, 0.f, 0.f};

    for (int kt = 0; kt < 16; ++kt) {
        const int k0 = kt * 32;
        float4 av[4];
#pragma unroll
        for (int i = 0; i < 4; ++i) {
            int lin = i * 256 + tid;
            int r = lin >> 3, c = (lin & 7) * 4;
            av[i] = *(const float4*)(x + (size_t)(rowBase + r) * 512 + k0 + c);
        }
        bf16x8 bv8[2];
#pragma unroll
        for (int i = 0; i < 2; ++i) {
            int lin = i * 256 + tid;
            int r = lin >> 2, c = (lin & 3) * 8;
            bv8[i] = *(const bf16x8*)(wqkvT + (size_t)(colBase + r) * 512 + k0 + c);
        }
        __syncthreads();
#pragma unroll
        for (int i = 0; i < 4; ++i) {
            int lin = i * 256 + tid;
            int r = lin >> 3, c = (lin & 7) * 4;
            ushort4 pk;
            pk.x = f2b(av[i].x); pk.y = f2b(av[i].y);
            pk.z = f2b(av[i].z); pk.w = f2b(av[i].w);
            *(ushort4*)&As[r * 40 + c] = pk;
        }
#pragma unroll
        for (int i = 0; i < 2; ++i) {
            int lin = i * 256 + tid;
            int r = lin >> 2, c = (lin & 3) * 8;
            *(bf16x8*)&Bs[r * 40 + c] = bv8[i];
        }
        __syncthreads();
        bf16x8 a[4], b[4];
#pragma unroll
        for (int ni = 0; ni < 4; ++ni)
            b[ni] = *(const bf16x8*)&Bs[(wc * 64 + ni * 16 + m) * 40 + qd * 8];
#pragma unroll
        for (int mi = 0; mi < 4; ++mi)
            a[mi] = *(const bf16x8*)&As[(wr * 64 + mi * 16 + m) * 40 + qd * 8];
#pragma unroll
        for (int mi = 0; mi < 4; ++mi)
#pragma unroll
            for (int ni = 0; ni < 4; ++ni)
                acc[mi][ni] = __builtin_amdgcn_mfma_f32_16x16x32_bf16(a[mi], b[ni], acc[mi][ni], 0, 0, 0);
    }

    const int which = colBase >> 9;  // uniform per block (128 | 512)
    u16* dst = (which == 0) ? qws : (which == 1) ? kws : vws;
#pragma unroll
    for (int mi = 0; mi < 4; ++mi) {
#pragma unroll
        for (int rr = 0; rr < 4; ++rr) {
            int row = rowBase + wr * 64 + mi * 16 + qd * 4 + rr;     // token in x-linear order
            int b_ = row >> 12, hh = (row >> 6) & 63, ww2 = row & 63;
            int rs = (hh + 60) & 63, cs = (ww2 + 60) & 63;           // shifted coords
            int win = b_ * 64 + (rs >> 3) * 8 + (cs >> 3);
            int t = (rs & 7) * 8 + (cs & 7);
#pragma unroll
            for (int ni = 0; ni < 4; ++ni) {
                int col = colBase + wc * 64 + ni * 16 + m;
                float v = acc[mi][ni][rr] + biasq[col];
                int h = (col >> 6) & 7, d = col & 63;
                if (which < 2)
                    dst[((size_t)(win * 8 + h) * 64 + t) * 64 + d] = f2b(v);
                else
                    dst[((size_t)(win * 8 + h) * 64 + d) * 64 + t] = f2b(v);
            }
        }
    }
}

// ---------------- attention: one wave per (window, head) ----------------
__global__ __launch_bounds__(256) void attn_kernel(const u16* __restrict__ qws,
        const u16* __restrict__ kws, const u16* __restrict__ vws,
        u16* __restrict__ ows) {
    __shared__ u16 P[4 * 64 * 72];
    const int tid = threadIdx.x, lane = tid & 63, wid = tid >> 6;
    const int task = blockIdx.x * 4 + wid;
    const int win = task >> 3, h = task & 7;
    const int m = lane & 15, qd = lane >> 4;
    const u16* Qp = qws + (size_t)(win * 8 + h) * 4096;
    const u16* Kp = kws + (size_t)(win * 8 + h) * 4096;
    const u16* Vp = vws + (size_t)(win * 8 + h) * 4096;

    bf16x8 qa[4][2], ka[4][2];
#pragma unroll
    for (int mi = 0; mi < 4; ++mi)
#pragma unroll
        for (int s = 0; s < 2; ++s) {
            qa[mi][s] = *(const bf16x8*)(Qp + (mi * 16 + m) * 64 + s * 32 + qd * 8);
            ka[mi][s] = *(const bf16x8*)(Kp + (mi * 16 + m) * 64 + s * 32 + qd * 8);
        }
    f32x4 sa[4][4];
#pragma unroll
    for (int i = 0; i < 4; ++i)
#pragma unroll
        for (int j = 0; j < 4; ++j) sa[i][j] = (f32x4){0.f, 0.f, 0.f, 0.f};
#pragma unroll
    for (int mi = 0; mi < 4; ++mi)
#pragma unroll
        for (int ni = 0; ni < 4; ++ni)
#pragma unroll
            for (int s = 0; s < 2; ++s)
                sa[mi][ni] = __builtin_amdgcn_mfma_f32_16x16x32_bf16(qa[mi][s], ka[ni][s], sa[mi][ni], 0, 0, 0);

    // softmax over columns (k tokens); row = mi*16 + qd*4 + rr, cols across 16 lanes x 4 ni
    const float c1 = 0.125f * 1.4426950408889634f;  // scale * log2(e)
    u16* Pl = P + wid * 64 * 72;
#pragma unroll
    for (int mi = 0; mi < 4; ++mi) {
#pragma unroll
        for (int rr = 0; rr < 4; ++rr) {
            float mx = -3.4e38f;
#pragma unroll
            for (int ni = 0; ni < 4; ++ni) mx = fmaxf(mx, sa[mi][ni][rr]);
            mx = fmaxf(mx, __shfl_xor(mx, 1, 64));
            mx = fmaxf(mx, __shfl_xor(mx, 2, 64));
            mx = fmaxf(mx, __shfl_xor(mx, 4, 64));
            mx = fmaxf(mx, __shfl_xor(mx, 8, 64));
            float sum = 0.f;
#pragma unroll
            for (int ni = 0; ni < 4; ++ni) {
                float p = exp2f((sa[mi][ni][rr] - mx) * c1);
                sa[mi][ni][rr] = p;
                sum += p;
            }
            sum += __shfl_xor(sum, 1, 64);
            sum += __shfl_xor(sum, 2, 64);
            sum += __shfl_xor(sum, 4, 64);
            sum += __shfl_xor(sum, 8, 64);
            float inv = 1.f / sum;
            int row = mi * 16 + qd * 4 + rr;
#pragma unroll
            for (int ni = 0; ni < 4; ++ni)
                Pl[row * 72 + ni * 16 + m] = f2b(sa[mi][ni][rr] * inv);
        }
    }

    // O = P @ V  (A-frags of P from LDS, B-frags from V^T global)
    bf16x8 pa[4][2], va[4][2];
#pragma unroll
    for (int mi = 0; mi < 4; ++mi)
#pragma unroll
        for (int s = 0; s < 2; ++s)
            pa[mi][s] = *(const bf16x8*)&Pl[(mi * 16 + m) * 72 + s * 32 + qd * 8];
#pragma unroll
    for (int ni = 0; ni < 4; ++ni)
#pragma unroll
        for (int s = 0; s < 2; ++s)
            va[ni][s] = *(const bf16x8*)(Vp + (ni * 16 + m) * 64 + s * 32 + qd * 8);
    f32x4 oa[4][4];
#pragma unroll
    for (int i = 0; i < 4; ++i)
#pragma unroll
        for (int j = 0; j < 4; ++j) oa[i][j] = (f32x4){0.f, 0.f, 0.f, 0.f};
#pragma unroll
    for (int mi = 0; mi < 4; ++mi)
#pragma unroll
        for (int ni = 0; ni < 4; ++ni)
#pragma unroll
            for (int s = 0; s < 2; ++s)
                oa[mi][ni] = __builtin_amdgcn_mfma_f32_16x16x32_bf16(pa[mi][s], va[ni][s], oa[mi][ni], 0, 0, 0);
#pragma unroll
    for (int mi = 0; mi < 4; ++mi)
#pragma unroll
        for (int rr = 0; rr < 4; ++rr) {
            int t = mi * 16 + qd * 4 + rr;
            u16* dst = ows + (size_t)(win * 64 + t) * 512 + h * 64;
#pragma unroll
            for (int ni = 0; ni < 4; ++ni)
                dst[ni * 16 + m] = f2b(oa[mi][ni][rr]);
        }
}

// ---------------- proj GEMM: M=32768 N=512 K=512, + bias + residual ----------------
__global__ __launch_bounds__(256) void proj_gemm(const u16* __restrict__ ows,
        const u16* __restrict__ woT, const float* __restrict__ bo,
        const float* __restrict__ x, float* __restrict__ out) {
    __shared__ u16 As[128 * 40];
    __shared__ u16 Bs[128 * 40];
    const int tid = threadIdx.x;
    const int lane = tid & 63, wid = tid >> 6;
    const int wr = wid >> 1, wc = wid & 1;
    const int m = lane & 15, qd = lane >> 4;
    const int rowBase = blockIdx.y * 128;   // row = win*64 + t
    const int colBase = blockIdx.x * 128;

    f32x4 acc[4][4];
#pragma unroll
    for (int i = 0; i < 4; ++i)
#pragma unroll
        for (int j = 0; j < 4; ++j) acc[i][j] = (f32x4){0.f, 0.f, 0.f, 0.f};

    for (int kt = 0; kt < 16; ++kt) {
        const int k0 = kt * 32;
        bf16x8 av8[2], bv8[2];
#pragma unroll
        for (int i = 0; i < 2; ++i) {
            int lin = i * 256 + tid;
            int r = lin >> 2, c = (lin & 3) * 8;
            av8[i] = *(const bf16x8*)(ows + (size_t)(rowBase + r) * 512 + k0 + c);
            bv8[i] = *(const bf16x8*)(woT + (size_t)(colBase + r) * 512 + k0 + c);
        }
        __syncthreads();
#pragma unroll
        for (int i = 0; i < 2; ++i) {
            int lin = i * 256 + tid;
            int r = lin >> 2, c = (lin & 3) * 8;
            *(bf16x8*)&As[r * 40 + c] = av8[i];
            *(bf16x8*)&Bs[r * 40 + c] = bv8[i];
        }
        __syncthreads();
        bf16x8 a[4], b[4];
#pragma unroll
        for (int ni = 0; ni < 4; ++ni)
            b[ni] = *(const bf16x8*)&Bs[(wc * 64 + ni * 16 + m) * 40 + qd * 8];
#pragma unroll
        for (int mi = 0; mi < 4; ++mi)
            a[mi] = *(const bf16x8*)&As[(wr * 64 + mi * 16 + m) * 40 + qd * 8];
#pragma unroll
        for (int mi = 0; mi < 4; ++mi)
#pragma unroll
            for (int ni = 0; ni < 4; ++ni)
                acc[mi][ni] = __builtin_amdgcn_mfma_f32_16x16x32_bf16(a[mi], b[ni], acc[mi][ni], 0, 0, 0);
    }

#pragma unroll
    for (int mi = 0; mi < 4; ++mi) {
#pragma unroll
        for (int rr = 0; rr < 4; ++rr) {
            int row = rowBase + wr * 64 + mi * 16 + qd * 4 + rr;   // win*64 + t
            int win = row >> 6, t = row & 63;
            int b_ = win >> 6, wh = (win >> 3) & 7, ww_ = win & 7;
            int ti = t >> 3, tj = t & 7;
            int hh = (wh * 8 + ti + 4) & 63;
            int www = (ww_ * 8 + tj + 4) & 63;
            size_t tok = (size_t)b_ * 4096 + hh * 64 + www;
#pragma unroll
            for (int ni = 0; ni < 4; ++ni) {
                int col = colBase + wc * 64 + ni * 16 + m;
                out[tok * 512 + col] = acc[mi][ni][rr] + bo[col] + x[tok * 512 + col];
            }
        }
    }
}

extern "C" void kernel_launch(void* const* d_in, const int* in_sizes, int n_in,
                              void* d_out, int out_size, void* d_ws, size_t ws_size,
                              hipStream_t stream) {
    const float* x  = (const float*)d_in[0];
    const float* wq = (const float*)d_in[1];
    const float* bq = (const float*)d_in[2];
    const float* wk = (const float*)d_in[3];
    const float* bk = (const float*)d_in[4];
    const float* wv = (const float*)d_in[5];
    const float* bv = (const float*)d_in[6];
    const float* wo = (const float*)d_in[7];
    const float* bo = (const float*)d_in[8];
    float* out = (float*)d_out;
    char* ws = (char*)d_ws;

    u16*   wqkvT = (u16*)ws;                               // 1536*512*2 = 1572864 B
    u16*   woT   = (u16*)(ws + 1572864);                   // 512*512*2  = 524288 B
    float* biasq = (float*)(ws + 1572864 + 524288);        // 1536*4     = 6144 B
    size_t off = 2103296;                                  // aligned
    u16* qws = (u16*)(ws + off);                           // 512*8*64*64 u16 = 32 MiB
    u16* kws = qws + (size_t)16777216;
    u16* vws = kws + (size_t)16777216;
    u16* ows = vws + (size_t)16777216;                     // [32768][512] u16

    const int prepN = 512 * 1536 + 512 * 512 + 1536;
    prep_kernel<<<dim3((prepN + 255) / 256), dim3(256), 0, stream>>>(
        wq, wk, wv, wo, bq, bk, bv, wqkvT, woT, biasq);
    qkv_gemm<<<dim3(12, 256), dim3(256), 0, stream>>>(x, wqkvT, biasq, qws, kws, vws);
    attn_kernel<<<dim3(1024), dim3(256), 0, stream>>>(qws, kws, vws, ows);
    proj_gemm<<<dim3(4, 256), dim3(256), 0, stream>>>(ows, woT, bo, x, out);
}

// Round 2
// 311.171 us; speedup vs baseline: 1.1377x; 1.1377x over previous
//
#include <hip/hip_runtime.h>

typedef unsigned short u16;
typedef short bf16x8 __attribute__((ext_vector_type(8)));
typedef float f32x4 __attribute__((ext_vector_type(4)));

typedef __attribute__((address_space(3))) unsigned int lds_uint;
typedef __attribute__((address_space(1))) const unsigned int glob_uint;

__device__ __forceinline__ void gll16(const void* g, void* l) {
    __builtin_amdgcn_global_load_lds((glob_uint*)g, (lds_uint*)l, 16, 0, 0);
}

__device__ __forceinline__ u16 f2b(float f) {
    union { float f; unsigned int u; } cv; cv.f = f;
    unsigned int u = cv.u;
    u += 0x7fffu + ((u >> 16) & 1u);
    return (u16)(u >> 16);
}

// ---------------- prep: weight transpose + bf16 convert ----------------
__global__ void prep_kernel(const float* __restrict__ wq, const float* __restrict__ wk,
                            const float* __restrict__ wv, const float* __restrict__ wo,
                            const float* __restrict__ bq, const float* __restrict__ bk,
                            const float* __restrict__ bv,
                            u16* __restrict__ wqkvT, u16* __restrict__ woT,
                            float* __restrict__ biasq) {
    int idx = blockIdx.x * 256 + threadIdx.x;
    const int N1 = 512 * 1536;
    const int N2 = 512 * 512;
    if (idx < N1) {
        int k = idx / 1536, n = idx % 1536;
        int which = n >> 9, nn = n & 511;
        const float* w = (which == 0) ? wq : (which == 1) ? wk : wv;
        wqkvT[n * 512 + k] = f2b(w[k * 512 + nn]);
    } else if (idx < N1 + N2) {
        int j = idx - N1;
        int k = j / 512, n = j % 512;
        woT[n * 512 + k] = f2b(wo[k * 512 + n]);
    } else if (idx < N1 + N2 + 1536) {
        int n = idx - N1 - N2;
        biasq[n] = (n < 512) ? bq[n] : (n < 1024) ? bk[n - 512] : bv[n - 1024];
    }
}

// ---------------- pre: x fp32 -> bf16, window-shift permuted ----------------
// xw[row][c], row = win*64 + t in shifted-window order.
__global__ __launch_bounds__(256) void pre_kernel(const float* __restrict__ x,
                                                  u16* __restrict__ xw) {
    int idx = blockIdx.x * 256 + threadIdx.x;      // 8 elems per thread
    int row = idx >> 6;
    int c = (idx & 63) * 8;
    int b_ = row >> 12, win = (row >> 6) & 63, t = row & 63;
    int wi = win >> 3, wj = win & 7, ti = t >> 3, tj = t & 7;
    int hh = (wi * 8 + ti + 4) & 63, ww = (wj * 8 + tj + 4) & 63;
    const float* src = x + ((size_t)b_ * 4096 + hh * 64 + ww) * 512 + c;
    float4 v0 = *(const float4*)src;
    float4 v1 = *(const float4*)(src + 4);
    ushort4 p0, p1;
    p0.x = f2b(v0.x); p0.y = f2b(v0.y); p0.z = f2b(v0.z); p0.w = f2b(v0.w);
    p1.x = f2b(v1.x); p1.y = f2b(v1.y); p1.z = f2b(v1.z); p1.w = f2b(v1.w);
    u16* dst = xw + (size_t)row * 512 + c;
    *(ushort4*)dst = p0;
    *(ushort4*)(dst + 4) = p1;
}

// ---------------- QKV GEMM: M=32768 N=1536 K=512 (m97 structure) ----------------
__global__ __launch_bounds__(256) void qkv_gemm(const u16* __restrict__ xw,
        const u16* __restrict__ wqkvT, const float* __restrict__ biasq,
        u16* __restrict__ qws, u16* __restrict__ kws, u16* __restrict__ vws) {
    __shared__ u16 As[128 * 32];   // unpadded, XOR-swizzled 16B chunks
    __shared__ u16 Bs[128 * 32];
    const int tid = threadIdx.x;
    const int lane = tid & 63, wid = tid >> 6;
    const int wr = wid >> 1, wc = wid & 1;
    const int m = lane & 15, qd = lane >> 4;
    const int rowBase = blockIdx.y * 128;
    const int colBase = blockIdx.x * 128;

    f32x4 acc[4][4];
#pragma unroll
    for (int i = 0; i < 4; ++i)
#pragma unroll
        for (int j = 0; j < 4; ++j) acc[i][j] = (f32x4){0.f, 0.f, 0.f, 0.f};

    for (int kt = 0; kt < 16; ++kt) {
        const int k0 = kt * 32;
        __syncthreads();
#pragma unroll
        for (int j = 0; j < 2; ++j) {
            int q = j * 256 + tid;
            int r = q >> 2;
            int cc = (q & 3) ^ (r & 3);           // logical 16B chunk (XOR swizzle)
            gll16(xw + (size_t)(rowBase + r) * 512 + k0 + cc * 8, &As[q * 8]);
            gll16(wqkvT + (size_t)(colBase + r) * 512 + k0 + cc * 8, &Bs[q * 8]);
        }
        __syncthreads();
        bf16x8 a[4], b[4];
#pragma unroll
        for (int ni = 0; ni < 4; ++ni) {
            int R = wc * 64 + ni * 16 + m;
            b[ni] = *(const bf16x8*)&Bs[R * 32 + ((qd ^ (R & 3)) * 8)];
        }
#pragma unroll
        for (int mi = 0; mi < 4; ++mi) {
            int R = wr * 64 + mi * 16 + m;
            a[mi] = *(const bf16x8*)&As[R * 32 + ((qd ^ (R & 3)) * 8)];
        }
#pragma unroll
        for (int mi = 0; mi < 4; ++mi)
#pragma unroll
            for (int ni = 0; ni < 4; ++ni)
                acc[mi][ni] = __builtin_amdgcn_mfma_f32_16x16x32_bf16(a[mi], b[ni], acc[mi][ni], 0, 0, 0);
    }

    const int which = colBase >> 9;  // uniform per block
    u16* dst = (which == 0) ? qws : (which == 1) ? kws : vws;
#pragma unroll
    for (int mi = 0; mi < 4; ++mi) {
#pragma unroll
        for (int rr = 0; rr < 4; ++rr) {
            int row = rowBase + wr * 64 + mi * 16 + qd * 4 + rr;  // win*64 + t
            int win = row >> 6, t = row & 63;
#pragma unroll
            for (int ni = 0; ni < 4; ++ni) {
                int col = colBase + wc * 64 + ni * 16 + m;
                float v = acc[mi][ni][rr] + biasq[col];
                int h = (col >> 6) & 7, d = col & 63;
                if (which < 2)
                    dst[((size_t)(win * 8 + h) * 64 + t) * 64 + d] = f2b(v);
                else
                    dst[((size_t)(win * 8 + h) * 64 + d) * 64 + t] = f2b(v);
            }
        }
    }
}

// ---------------- attention: one wave per (window, head) ----------------
__global__ __launch_bounds__(256) void attn_kernel(const u16* __restrict__ qws,
        const u16* __restrict__ kws, const u16* __restrict__ vws,
        u16* __restrict__ ows) {
    __shared__ u16 P[4 * 64 * 72];
    const int tid = threadIdx.x, lane = tid & 63, wid = tid >> 6;
    const int task = blockIdx.x * 4 + wid;
    const int win = task >> 3, h = task & 7;
    const int m = lane & 15, qd = lane >> 4;
    const u16* Qp = qws + (size_t)(win * 8 + h) * 4096;
    const u16* Kp = kws + (size_t)(win * 8 + h) * 4096;
    const u16* Vp = vws + (size_t)(win * 8 + h) * 4096;

    bf16x8 qa[4][2], ka[4][2];
#pragma unroll
    for (int mi = 0; mi < 4; ++mi)
#pragma unroll
        for (int s = 0; s < 2; ++s) {
            qa[mi][s] = *(const bf16x8*)(Qp + (mi * 16 + m) * 64 + s * 32 + qd * 8);
            ka[mi][s] = *(const bf16x8*)(Kp + (mi * 16 + m) * 64 + s * 32 + qd * 8);
        }
    f32x4 sa[4][4];
#pragma unroll
    for (int i = 0; i < 4; ++i)
#pragma unroll
        for (int j = 0; j < 4; ++j) sa[i][j] = (f32x4){0.f, 0.f, 0.f, 0.f};
#pragma unroll
    for (int mi = 0; mi < 4; ++mi)
#pragma unroll
        for (int ni = 0; ni < 4; ++ni)
#pragma unroll
            for (int s = 0; s < 2; ++s)
                sa[mi][ni] = __builtin_amdgcn_mfma_f32_16x16x32_bf16(qa[mi][s], ka[ni][s], sa[mi][ni], 0, 0, 0);

    const float c1 = 0.125f * 1.4426950408889634f;
    u16* Pl = P + wid * 64 * 72;
#pragma unroll
    for (int mi = 0; mi < 4; ++mi) {
#pragma unroll
        for (int rr = 0; rr < 4; ++rr) {
            float mx = -3.4e38f;
#pragma unroll
            for (int ni = 0; ni < 4; ++ni) mx = fmaxf(mx, sa[mi][ni][rr]);
            mx = fmaxf(mx, __shfl_xor(mx, 1, 64));
            mx = fmaxf(mx, __shfl_xor(mx, 2, 64));
            mx = fmaxf(mx, __shfl_xor(mx, 4, 64));
            mx = fmaxf(mx, __shfl_xor(mx, 8, 64));
            float sum = 0.f;
#pragma unroll
            for (int ni = 0; ni < 4; ++ni) {
                float p = exp2f((sa[mi][ni][rr] - mx) * c1);
                sa[mi][ni][rr] = p;
                sum += p;
            }
            sum += __shfl_xor(sum, 1, 64);
            sum += __shfl_xor(sum, 2, 64);
            sum += __shfl_xor(sum, 4, 64);
            sum += __shfl_xor(sum, 8, 64);
            float inv = 1.f / sum;
            int row = mi * 16 + qd * 4 + rr;
#pragma unroll
            for (int ni = 0; ni < 4; ++ni)
                Pl[row * 72 + ni * 16 + m] = f2b(sa[mi][ni][rr] * inv);
        }
    }

    bf16x8 pa[4][2], va[4][2];
#pragma unroll
    for (int mi = 0; mi < 4; ++mi)
#pragma unroll
        for (int s = 0; s < 2; ++s)
            pa[mi][s] = *(const bf16x8*)&Pl[(mi * 16 + m) * 72 + s * 32 + qd * 8];
#pragma unroll
    for (int ni = 0; ni < 4; ++ni)
#pragma unroll
        for (int s = 0; s < 2; ++s)
            va[ni][s] = *(const bf16x8*)(Vp + (ni * 16 + m) * 64 + s * 32 + qd * 8);
    f32x4 oa[4][4];
#pragma unroll
    for (int i = 0; i < 4; ++i)
#pragma unroll
        for (int j = 0; j < 4; ++j) oa[i][j] = (f32x4){0.f, 0.f, 0.f, 0.f};
#pragma unroll
    for (int mi = 0; mi < 4; ++mi)
#pragma unroll
        for (int ni = 0; ni < 4; ++ni)
#pragma unroll
            for (int s = 0; s < 2; ++s)
                oa[mi][ni] = __builtin_amdgcn_mfma_f32_16x16x32_bf16(pa[mi][s], va[ni][s], oa[mi][ni], 0, 0, 0);
#pragma unroll
    for (int mi = 0; mi < 4; ++mi)
#pragma unroll
        for (int rr = 0; rr < 4; ++rr) {
            int t = mi * 16 + qd * 4 + rr;
            u16* dst = ows + (size_t)(win * 64 + t) * 512 + h * 64;
#pragma unroll
            for (int ni = 0; ni < 4; ++ni)
                dst[ni * 16 + m] = f2b(oa[mi][ni][rr]);
        }
}

// ---------------- proj GEMM: M=32768 N=512 K=512, + bias + residual ----------------
__global__ __launch_bounds__(256) void proj_gemm(const u16* __restrict__ ows,
        const u16* __restrict__ woT, const float* __restrict__ bo,
        const float* __restrict__ x, float* __restrict__ out) {
    __shared__ u16 As[128 * 32];
    __shared__ u16 Bs[128 * 32];
    const int tid = threadIdx.x;
    const int lane = tid & 63, wid = tid >> 6;
    const int wr = wid >> 1, wc = wid & 1;
    const int m = lane & 15, qd = lane >> 4;
    const int rowBase = blockIdx.y * 128;
    const int colBase = blockIdx.x * 128;

    f32x4 acc[4][4];
#pragma unroll
    for (int i = 0; i < 4; ++i)
#pragma unroll
        for (int j = 0; j < 4; ++j) acc[i][j] = (f32x4){0.f, 0.f, 0.f, 0.f};

    for (int kt = 0; kt < 16; ++kt) {
        const int k0 = kt * 32;
        __syncthreads();
#pragma unroll
        for (int j = 0; j < 2; ++j) {
            int q = j * 256 + tid;
            int r = q >> 2;
            int cc = (q & 3) ^ (r & 3);
            gll16(ows + (size_t)(rowBase + r) * 512 + k0 + cc * 8, &As[q * 8]);
            gll16(woT + (size_t)(colBase + r) * 512 + k0 + cc * 8, &Bs[q * 8]);
        }
        __syncthreads();
        bf16x8 a[4], b[4];
#pragma unroll
        for (int ni = 0; ni < 4; ++ni) {
            int R = wc * 64 + ni * 16 + m;
            b[ni] = *(const bf16x8*)&Bs[R * 32 + ((qd ^ (R & 3)) * 8)];
        }
#pragma unroll
        for (int mi = 0; mi < 4; ++mi) {
            int R = wr * 64 + mi * 16 + m;
            a[mi] = *(const bf16x8*)&As[R * 32 + ((qd ^ (R & 3)) * 8)];
        }
#pragma unroll
        for (int mi = 0; mi < 4; ++mi)
#pragma unroll
            for (int ni = 0; ni < 4; ++ni)
                acc[mi][ni] = __builtin_amdgcn_mfma_f32_16x16x32_bf16(a[mi], b[ni], acc[mi][ni], 0, 0, 0);
    }

#pragma unroll
    for (int mi = 0; mi < 4; ++mi) {
#pragma unroll
        for (int rr = 0; rr < 4; ++rr) {
            int row = rowBase + wr * 64 + mi * 16 + qd * 4 + rr;   // win*64 + t
            int win = row >> 6, t = row & 63;
            int b_ = win >> 6, wh = (win >> 3) & 7, ww_ = win & 7;
            int ti = t >> 3, tj = t & 7;
            int hh = (wh * 8 + ti + 4) & 63;
            int www = (ww_ * 8 + tj + 4) & 63;
            size_t tok = (size_t)b_ * 4096 + hh * 64 + www;
#pragma unroll
            for (int ni = 0; ni < 4; ++ni) {
                int col = colBase + wc * 64 + ni * 16 + m;
                out[tok * 512 + col] = acc[mi][ni][rr] + bo[col] + x[tok * 512 + col];
            }
        }
    }
}

extern "C" void kernel_launch(void* const* d_in, const int* in_sizes, int n_in,
                              void* d_out, int out_size, void* d_ws, size_t ws_size,
                              hipStream_t stream) {
    const float* x  = (const float*)d_in[0];
    const float* wq = (const float*)d_in[1];
    const float* bq = (const float*)d_in[2];
    const float* wk = (const float*)d_in[3];
    const float* bk = (const float*)d_in[4];
    const float* wv = (const float*)d_in[5];
    const float* bv = (const float*)d_in[6];
    const float* wo = (const float*)d_in[7];
    const float* bo = (const float*)d_in[8];
    float* out = (float*)d_out;
    char* ws = (char*)d_ws;

    u16*   wqkvT = (u16*)ws;                               // 1536*512*2
    u16*   woT   = (u16*)(ws + 1572864);                   // 512*512*2
    float* biasq = (float*)(ws + 1572864 + 524288);        // 1536*4
    size_t off = 2103296;
    u16* xw  = (u16*)(ws + off);                           // 32768*512 u16 = 32 MiB
    u16* qws = xw + (size_t)16777216;                      // 32 MiB each
    u16* kws = qws + (size_t)16777216;
    u16* vws = kws + (size_t)16777216;
    u16* ows = xw;                                         // alias: xw dead after qkv_gemm

    const int prepN = 512 * 1536 + 512 * 512 + 1536;
    prep_kernel<<<dim3((prepN + 255) / 256), dim3(256), 0, stream>>>(
        wq, wk, wv, wo, bq, bk, bv, wqkvT, woT, biasq);
    pre_kernel<<<dim3(8192), dim3(256), 0, stream>>>(x, xw);
    qkv_gemm<<<dim3(12, 256), dim3(256), 0, stream>>>(xw, wqkvT, biasq, qws, kws, vws);
    attn_kernel<<<dim3(1024), dim3(256), 0, stream>>>(qws, kws, vws, ows);
    proj_gemm<<<dim3(4, 256), dim3(256), 0, stream>>>(ows, woT, bo, x, out);
}

// Round 3
// 278.272 us; speedup vs baseline: 1.2722x; 1.1182x over previous
//
#include <hip/hip_runtime.h>

typedef unsigned short u16;
typedef short bf16x8 __attribute__((ext_vector_type(8)));
typedef float f32x4 __attribute__((ext_vector_type(4)));

typedef __attribute__((address_space(3))) unsigned int lds_uint;
typedef __attribute__((address_space(1))) const unsigned int glob_uint;

__device__ __forceinline__ void gll16(const void* g, void* l) {
    __builtin_amdgcn_global_load_lds((glob_uint*)g, (lds_uint*)l, 16, 0, 0);
}

__device__ __forceinline__ u16 f2b(float f) {
    union { float f; unsigned int u; } cv; cv.f = f;
    unsigned int u = cv.u;
    u += 0x7fffu + ((u >> 16) & 1u);
    return (u16)(u >> 16);
}

// ---------------- prep: weight transpose + bf16 convert ----------------
__global__ void prep_kernel(const float* __restrict__ wq, const float* __restrict__ wk,
                            const float* __restrict__ wv, const float* __restrict__ wo,
                            const float* __restrict__ bq, const float* __restrict__ bk,
                            const float* __restrict__ bv,
                            u16* __restrict__ wqkvT, u16* __restrict__ woT,
                            float* __restrict__ biasq) {
    int idx = blockIdx.x * 256 + threadIdx.x;
    const int N1 = 512 * 1536;
    const int N2 = 512 * 512;
    if (idx < N1) {
        int k = idx / 1536, n = idx % 1536;
        int which = n >> 9, nn = n & 511;
        const float* w = (which == 0) ? wq : (which == 1) ? wk : wv;
        wqkvT[n * 512 + k] = f2b(w[k * 512 + nn]);
    } else if (idx < N1 + N2) {
        int j = idx - N1;
        int k = j / 512, n = j % 512;
        woT[n * 512 + k] = f2b(wo[k * 512 + n]);
    } else if (idx < N1 + N2 + 1536) {
        int n = idx - N1 - N2;
        biasq[n] = (n < 512) ? bq[n] : (n < 1024) ? bk[n - 512] : bv[n - 1024];
    }
}

// ---------------- pre: x fp32 -> bf16, window-shift permuted ----------------
__global__ __launch_bounds__(256) void pre_kernel(const float* __restrict__ x,
                                                  u16* __restrict__ xw) {
    int idx = blockIdx.x * 256 + threadIdx.x;      // 8 elems per thread
    int row = idx >> 6;
    int c = (idx & 63) * 8;
    int b_ = row >> 12, win = (row >> 6) & 63, t = row & 63;
    int wi = win >> 3, wj = win & 7, ti = t >> 3, tj = t & 7;
    int hh = (wi * 8 + ti + 4) & 63, ww = (wj * 8 + tj + 4) & 63;
    const float* src = x + ((size_t)b_ * 4096 + hh * 64 + ww) * 512 + c;
    float4 v0 = *(const float4*)src;
    float4 v1 = *(const float4*)(src + 4);
    ushort4 p0, p1;
    p0.x = f2b(v0.x); p0.y = f2b(v0.y); p0.z = f2b(v0.z); p0.w = f2b(v0.w);
    p1.x = f2b(v1.x); p1.y = f2b(v1.y); p1.z = f2b(v1.z); p1.w = f2b(v1.w);
    u16* dst = xw + (size_t)row * 512 + c;
    *(ushort4*)dst = p0;
    *(ushort4*)(dst + 4) = p1;
}

// ---------------- QKV GEMM: M=32768 N=1536 K=512, BK=64 ----------------
// Output: qkvb[row][1536] row-major bf16 (coalesced).
__global__ __launch_bounds__(256) void qkv_gemm(const u16* __restrict__ xw,
        const u16* __restrict__ wqkvT, const float* __restrict__ biasq,
        u16* __restrict__ qkvb) {
    __shared__ u16 As[128 * 64];   // 16 KB, rows of 8 x 16B chunks, XOR-8 swizzled
    __shared__ u16 Bs[128 * 64];
    const int tid = threadIdx.x;
    const int lane = tid & 63, wid = tid >> 6;
    const int wr = wid >> 1, wc = wid & 1;
    const int m = lane & 15, qd = lane >> 4;
    const int rowBase = blockIdx.y * 128;
    const int colBase = blockIdx.x * 128;
    const int c8 = (lane & 7) ^ (lane >> 3);   // global chunk this lane stages

    f32x4 acc[4][4];
#pragma unroll
    for (int i = 0; i < 4; ++i)
#pragma unroll
        for (int j = 0; j < 4; ++j) acc[i][j] = (f32x4){0.f, 0.f, 0.f, 0.f};

    for (int kt = 0; kt < 8; ++kt) {
        const int k0 = kt * 64;
        __syncthreads();
#pragma unroll
        for (int j = 0; j < 4; ++j) {
            int q = (j * 4 + wid) * 64 + lane;          // chunk slot, lane-contiguous
            int r = (j * 4 + wid) * 8 + (lane >> 3);    // tile row
            gll16(xw + (size_t)(rowBase + r) * 512 + k0 + c8 * 8, &As[q * 8]);
            gll16(wqkvT + (size_t)(colBase + r) * 512 + k0 + c8 * 8, &Bs[q * 8]);
        }
        __syncthreads();
#pragma unroll
        for (int s = 0; s < 2; ++s) {
            bf16x8 a[4], b[4];
#pragma unroll
            for (int ni = 0; ni < 4; ++ni) {
                int R = wc * 64 + ni * 16 + m;
                b[ni] = *(const bf16x8*)&Bs[R * 64 + (((s * 4 + qd) ^ (R & 7)) * 8)];
            }
#pragma unroll
            for (int mi = 0; mi < 4; ++mi) {
                int R = wr * 64 + mi * 16 + m;
                a[mi] = *(const bf16x8*)&As[R * 64 + (((s * 4 + qd) ^ (R & 7)) * 8)];
            }
#pragma unroll
            for (int mi = 0; mi < 4; ++mi)
#pragma unroll
                for (int ni = 0; ni < 4; ++ni)
                    acc[mi][ni] = __builtin_amdgcn_mfma_f32_16x16x32_bf16(a[mi], b[ni], acc[mi][ni], 0, 0, 0);
        }
    }

    float bias[4];
#pragma unroll
    for (int ni = 0; ni < 4; ++ni) bias[ni] = biasq[colBase + wc * 64 + ni * 16 + m];
#pragma unroll
    for (int mi = 0; mi < 4; ++mi) {
#pragma unroll
        for (int rr = 0; rr < 4; ++rr) {
            int row = rowBase + wr * 64 + mi * 16 + qd * 4 + rr;
            u16* dst = qkvb + (size_t)row * 1536 + colBase + wc * 64;
#pragma unroll
            for (int ni = 0; ni < 4; ++ni)
                dst[ni * 16 + m] = f2b(acc[mi][ni][rr] + bias[ni]);
        }
    }
}

// ---------------- attention: one wave per (window, head) ----------------
// qkvb rows: win*64 + t; cols: [0,512)=Q, [512,1024)=K, [1024,1536)=V.
__global__ __launch_bounds__(256) void attn_kernel(const u16* __restrict__ qkvb,
                                                   u16* __restrict__ ows) {
    __shared__ u16 Sb[4 * 64 * 72];   // per-wave scratch: P, then V (36,864 B)
    const int tid = threadIdx.x, lane = tid & 63, wid = tid >> 6;
    const int task = blockIdx.x * 4 + wid;
    const int win = task >> 3, h = task & 7;
    const int m = lane & 15, qd = lane >> 4;
    const u16* base = qkvb + (size_t)win * 64 * 1536;
    u16* Sl = Sb + wid * 64 * 72;

    // Q, K fragments (16B loads)
    bf16x8 qa[4][2], ka[4][2];
#pragma unroll
    for (int mi = 0; mi < 4; ++mi)
#pragma unroll
        for (int s = 0; s < 2; ++s) {
            const u16* p = base + (size_t)(mi * 16 + m) * 1536 + h * 64 + s * 32 + qd * 8;
            qa[mi][s] = *(const bf16x8*)p;
            ka[mi][s] = *(const bf16x8*)(p + 512);
        }
    // V rows into registers (coalesced 16B loads)
    bf16x8 vr[8];
#pragma unroll
    for (int i = 0; i < 8; ++i) {
        int r = i * 8 + (lane >> 3);
        vr[i] = *(const bf16x8*)(base + (size_t)r * 1536 + 1024 + h * 64 + (lane & 7) * 8);
    }

    f32x4 sa[4][4];
#pragma unroll
    for (int i = 0; i < 4; ++i)
#pragma unroll
        for (int j = 0; j < 4; ++j) sa[i][j] = (f32x4){0.f, 0.f, 0.f, 0.f};
#pragma unroll
    for (int mi = 0; mi < 4; ++mi)
#pragma unroll
        for (int ni = 0; ni < 4; ++ni)
#pragma unroll
            for (int s = 0; s < 2; ++s)
                sa[mi][ni] = __builtin_amdgcn_mfma_f32_16x16x32_bf16(qa[mi][s], ka[ni][s], sa[mi][ni], 0, 0, 0);

    // softmax; write P into Sl (row stride 72)
    const float c1 = 0.125f * 1.4426950408889634f;
#pragma unroll
    for (int mi = 0; mi < 4; ++mi) {
#pragma unroll
        for (int rr = 0; rr < 4; ++rr) {
            float mx = -3.4e38f;
#pragma unroll
            for (int ni = 0; ni < 4; ++ni) mx = fmaxf(mx, sa[mi][ni][rr]);
            mx = fmaxf(mx, __shfl_xor(mx, 1, 64));
            mx = fmaxf(mx, __shfl_xor(mx, 2, 64));
            mx = fmaxf(mx, __shfl_xor(mx, 4, 64));
            mx = fmaxf(mx, __shfl_xor(mx, 8, 64));
            float sum = 0.f;
#pragma unroll
            for (int ni = 0; ni < 4; ++ni) {
                float p = exp2f((sa[mi][ni][rr] - mx) * c1);
                sa[mi][ni][rr] = p;
                sum += p;
            }
            sum += __shfl_xor(sum, 1, 64);
            sum += __shfl_xor(sum, 2, 64);
            sum += __shfl_xor(sum, 4, 64);
            sum += __shfl_xor(sum, 8, 64);
            float inv = 1.f / sum;
            int row = mi * 16 + qd * 4 + rr;
#pragma unroll
            for (int ni = 0; ni < 4; ++ni)
                Sl[row * 72 + ni * 16 + m] = f2b(sa[mi][ni][rr] * inv);
        }
    }

    // P A-fragments
    bf16x8 pa[4][2];
#pragma unroll
    for (int mi = 0; mi < 4; ++mi)
#pragma unroll
        for (int s = 0; s < 2; ++s)
            pa[mi][s] = *(const bf16x8*)&Sl[(mi * 16 + m) * 72 + s * 32 + qd * 8];

    // reuse Sl for V (untransposed, stride 72); then gather B-fragments
#pragma unroll
    for (int i = 0; i < 8; ++i) {
        int r = i * 8 + (lane >> 3);
        *(bf16x8*)&Sl[r * 72 + (lane & 7) * 8] = vr[i];
    }
    f32x4 oa[4][4];
#pragma unroll
    for (int i = 0; i < 4; ++i)
#pragma unroll
        for (int j = 0; j < 4; ++j) oa[i][j] = (f32x4){0.f, 0.f, 0.f, 0.f};
#pragma unroll
    for (int ni = 0; ni < 4; ++ni)
#pragma unroll
        for (int s = 0; s < 2; ++s) {
            bf16x8 v;
#pragma unroll
            for (int j = 0; j < 8; ++j)
                ((short*)&v)[j] = (short)Sl[(s * 32 + qd * 8 + j) * 72 + ni * 16 + m];
#pragma unroll
            for (int mi = 0; mi < 4; ++mi)
                oa[mi][ni] = __builtin_amdgcn_mfma_f32_16x16x32_bf16(pa[mi][s], v, oa[mi][ni], 0, 0, 0);
        }

#pragma unroll
    for (int mi = 0; mi < 4; ++mi)
#pragma unroll
        for (int rr = 0; rr < 4; ++rr) {
            int t = mi * 16 + qd * 4 + rr;
            u16* dst = ows + (size_t)(win * 64 + t) * 512 + h * 64;
#pragma unroll
            for (int ni = 0; ni < 4; ++ni)
                dst[ni * 16 + m] = f2b(oa[mi][ni][rr]);
        }
}

// ---------------- proj GEMM: M=32768 N=512 K=512, BK=64, + bias + residual ----------------
__global__ __launch_bounds__(256) void proj_gemm(const u16* __restrict__ ows,
        const u16* __restrict__ woT, const float* __restrict__ bo,
        const float* __restrict__ x, float* __restrict__ out) {
    __shared__ u16 As[128 * 64];
    __shared__ u16 Bs[128 * 64];
    const int tid = threadIdx.x;
    const int lane = tid & 63, wid = tid >> 6;
    const int wr = wid >> 1, wc = wid & 1;
    const int m = lane & 15, qd = lane >> 4;
    const int rowBase = blockIdx.y * 128;
    const int colBase = blockIdx.x * 128;
    const int c8 = (lane & 7) ^ (lane >> 3);

    f32x4 acc[4][4];
#pragma unroll
    for (int i = 0; i < 4; ++i)
#pragma unroll
        for (int j = 0; j < 4; ++j) acc[i][j] = (f32x4){0.f, 0.f, 0.f, 0.f};

    for (int kt = 0; kt < 8; ++kt) {
        const int k0 = kt * 64;
        __syncthreads();
#pragma unroll
        for (int j = 0; j < 4; ++j) {
            int q = (j * 4 + wid) * 64 + lane;
            int r = (j * 4 + wid) * 8 + (lane >> 3);
            gll16(ows + (size_t)(rowBase + r) * 512 + k0 + c8 * 8, &As[q * 8]);
            gll16(woT + (size_t)(colBase + r) * 512 + k0 + c8 * 8, &Bs[q * 8]);
        }
        __syncthreads();
#pragma unroll
        for (int s = 0; s < 2; ++s) {
            bf16x8 a[4], b[4];
#pragma unroll
            for (int ni = 0; ni < 4; ++ni) {
                int R = wc * 64 + ni * 16 + m;
                b[ni] = *(const bf16x8*)&Bs[R * 64 + (((s * 4 + qd) ^ (R & 7)) * 8)];
            }
#pragma unroll
            for (int mi = 0; mi < 4; ++mi) {
                int R = wr * 64 + mi * 16 + m;
                a[mi] = *(const bf16x8*)&As[R * 64 + (((s * 4 + qd) ^ (R & 7)) * 8)];
            }
#pragma unroll
            for (int mi = 0; mi < 4; ++mi)
#pragma unroll
                for (int ni = 0; ni < 4; ++ni)
                    acc[mi][ni] = __builtin_amdgcn_mfma_f32_16x16x32_bf16(a[mi], b[ni], acc[mi][ni], 0, 0, 0);
        }
    }

#pragma unroll
    for (int mi = 0; mi < 4; ++mi) {
#pragma unroll
        for (int rr = 0; rr < 4; ++rr) {
            int row = rowBase + wr * 64 + mi * 16 + qd * 4 + rr;   // win*64 + t
            int win = row >> 6, t = row & 63;
            int b_ = win >> 6, wh = (win >> 3) & 7, ww_ = win & 7;
            int ti = t >> 3, tj = t & 7;
            int hh = (wh * 8 + ti + 4) & 63;
            int www = (ww_ * 8 + tj + 4) & 63;
            size_t tok = (size_t)b_ * 4096 + hh * 64 + www;
#pragma unroll
            for (int ni = 0; ni < 4; ++ni) {
                int col = colBase + wc * 64 + ni * 16 + m;
                out[tok * 512 + col] = acc[mi][ni][rr] + bo[col] + x[tok * 512 + col];
            }
        }
    }
}

extern "C" void kernel_launch(void* const* d_in, const int* in_sizes, int n_in,
                              void* d_out, int out_size, void* d_ws, size_t ws_size,
                              hipStream_t stream) {
    const float* x  = (const float*)d_in[0];
    const float* wq = (const float*)d_in[1];
    const float* bq = (const float*)d_in[2];
    const float* wk = (const float*)d_in[3];
    const float* bk = (const float*)d_in[4];
    const float* wv = (const float*)d_in[5];
    const float* bv = (const float*)d_in[6];
    const float* wo = (const float*)d_in[7];
    const float* bo = (const float*)d_in[8];
    float* out = (float*)d_out;
    char* ws = (char*)d_ws;

    u16*   wqkvT = (u16*)ws;                               // 1536*512*2
    u16*   woT   = (u16*)(ws + 1572864);                   // 512*512*2
    float* biasq = (float*)(ws + 1572864 + 524288);        // 1536*4
    size_t off = 2103296;
    u16* xw   = (u16*)(ws + off);                          // 32768*512  u16 = 32 MiB
    u16* qkvb = xw + (size_t)16777216;                     // 32768*1536 u16 = 96 MiB
    u16* ows  = xw;                                        // alias: xw dead after qkv_gemm

    const int prepN = 512 * 1536 + 512 * 512 + 1536;
    prep_kernel<<<dim3((prepN + 255) / 256), dim3(256), 0, stream>>>(
        wq, wk, wv, wo, bq, bk, bv, wqkvT, woT, biasq);
    pre_kernel<<<dim3(8192), dim3(256), 0, stream>>>(x, xw);
    qkv_gemm<<<dim3(12, 256), dim3(256), 0, stream>>>(xw, wqkvT, biasq, qkvb);
    attn_kernel<<<dim3(1024), dim3(256), 0, stream>>>(qkvb, ows);
    proj_gemm<<<dim3(4, 256), dim3(256), 0, stream>>>(ows, woT, bo, x, out);
}

// Round 4
// 275.572 us; speedup vs baseline: 1.2847x; 1.0098x over previous
//
#include <hip/hip_runtime.h>

typedef unsigned short u16;
typedef short bf16x8 __attribute__((ext_vector_type(8)));
typedef float f32x4 __attribute__((ext_vector_type(4)));

typedef __attribute__((address_space(3))) unsigned int lds_uint;
typedef __attribute__((address_space(1))) const unsigned int glob_uint;

__device__ __forceinline__ void gll16(const void* g, void* l) {
    __builtin_amdgcn_global_load_lds((glob_uint*)g, (lds_uint*)l, 16, 0, 0);
}

__device__ __forceinline__ u16 f2b(float f) {
    union { float f; unsigned int u; } cv; cv.f = f;
    unsigned int u = cv.u;
    u += 0x7fffu + ((u >> 16) & 1u);
    return (u16)(u >> 16);
}

__device__ __forceinline__ uint2 pack4(float a, float b, float c, float d) {
    uint2 r;
    r.x = (unsigned int)f2b(a) | ((unsigned int)f2b(b) << 16);
    r.y = (unsigned int)f2b(c) | ((unsigned int)f2b(d) << 16);
    return r;
}

// ---------------- prep: head-major weight reorder + bf16 convert ----------------
// wqkvh[(h*192+j)][k] : j in [0,64)=Q, [64,128)=K, [128,192)=V (output dim j&63)
// woT[n][k] = wo[k][n]; biash[h*192+j]
__global__ void prep_kernel(const float* __restrict__ wq, const float* __restrict__ wk,
                            const float* __restrict__ wv, const float* __restrict__ wo,
                            const float* __restrict__ bq, const float* __restrict__ bk,
                            const float* __restrict__ bv,
                            u16* __restrict__ wqkvh, u16* __restrict__ woT,
                            float* __restrict__ biash) {
    int idx = blockIdx.x * 256 + threadIdx.x;
    const int N1 = 512 * 1536;
    const int N2 = 512 * 512;
    if (idx < N1) {
        int k = idx / 1536, n2 = idx % 1536;
        int h = n2 / 192, j = n2 % 192;
        const float* w = (j < 64) ? wq : (j < 128) ? wk : wv;
        wqkvh[(size_t)n2 * 512 + k] = f2b(w[k * 512 + h * 64 + (j & 63)]);
    } else if (idx < N1 + N2) {
        int i = idx - N1;
        int k = i / 512, n = i % 512;
        woT[n * 512 + k] = f2b(wo[k * 512 + n]);
    } else if (idx < N1 + N2 + 1536) {
        int n2 = idx - N1 - N2;
        int h = n2 / 192, j = n2 % 192;
        const float* b = (j < 64) ? bq : (j < 128) ? bk : bv;
        biash[n2] = b[h * 64 + (j & 63)];
    }
}

// ---------------- pre: x fp32 -> bf16, window-shift permuted ----------------
__global__ __launch_bounds__(256) void pre_kernel(const float* __restrict__ x,
                                                  u16* __restrict__ xw) {
    int idx = blockIdx.x * 256 + threadIdx.x;      // 8 elems per thread
    int row = idx >> 6;
    int c = (idx & 63) * 8;
    int b_ = row >> 12, win = (row >> 6) & 63, t = row & 63;
    int wi = win >> 3, wj = win & 7, ti = t >> 3, tj = t & 7;
    int hh = (wi * 8 + ti + 4) & 63, ww = (wj * 8 + tj + 4) & 63;
    const float* src = x + ((size_t)b_ * 4096 + hh * 64 + ww) * 512 + c;
    float4 v0 = *(const float4*)src;
    float4 v1 = *(const float4*)(src + 4);
    ushort4 p0, p1;
    p0.x = f2b(v0.x); p0.y = f2b(v0.y); p0.z = f2b(v0.z); p0.w = f2b(v0.w);
    p1.x = f2b(v1.x); p1.y = f2b(v1.y); p1.z = f2b(v1.z); p1.w = f2b(v1.w);
    u16* dst = xw + (size_t)row * 512 + c;
    *(ushort4*)dst = p0;
    *(ushort4*)(dst + 4) = p1;
}

// ---------------- fused QKV + attention: one block per window ----------------
// Per head: GEMM 64x192x512 (A=xw window rows, B=wqkvh head slab), epilogue
// writes Q,K (swapped tiles, packed b64) and V^T into LDS, then attention,
// packed O stores to ows[tok][h*64+d].
// LDS map (u16 units): As[0,4096) Bs[4096,16384) QKs@16384 (64x136)
//                      VT@25088 (64x72)  Pbuf aliases staging (wid*2176)
__global__ __launch_bounds__(256) void fused_qkv_attn(const u16* __restrict__ xw,
        const u16* __restrict__ wqkvh, const float* __restrict__ biash,
        u16* __restrict__ ows) {
    __shared__ u16 S[29696];
    const int tid = threadIdx.x;
    const int lane = tid & 63, wid = tid >> 6;
    const int wr = wid >> 1, wc = wid & 1;
    const int m = lane & 15, qd = lane >> 4;
    const int win = blockIdx.x;
    const int rowBase = win * 64;

    u16* As  = S;
    u16* Bs  = S + 4096;
    u16* QKs = S + 16384;
    u16* VT  = S + 25088;
    u16* Pw  = S + wid * 2176;   // per-wave 16x136, aliases staging

    for (int h = 0; h < 8; ++h) {
        const u16* Bsrc = wqkvh + (size_t)h * 192 * 512;
        f32x4 acc[2][6];
#pragma unroll
        for (int i = 0; i < 2; ++i)
#pragma unroll
            for (int j = 0; j < 6; ++j) acc[i][j] = (f32x4){0.f, 0.f, 0.f, 0.f};

        for (int kt = 0; kt < 8; ++kt) {
            const int k0 = kt * 64;
            __syncthreads();
#pragma unroll
            for (int j = 0; j < 2; ++j) {
                int q = j * 256 + tid;
                int r = q >> 3, c = (q & 7) ^ (r & 7);
                gll16(xw + (size_t)(rowBase + r) * 512 + k0 + c * 8, As + q * 8);
            }
#pragma unroll
            for (int j = 0; j < 6; ++j) {
                int q = j * 256 + tid;
                int r = q >> 3, c = (q & 7) ^ (r & 7);
                gll16(Bsrc + (size_t)r * 512 + k0 + c * 8, Bs + q * 8);
            }
            __syncthreads();
#pragma unroll
            for (int s = 0; s < 2; ++s) {
                bf16x8 a[2], b[6];
#pragma unroll
                for (int ni = 0; ni < 6; ++ni) {
                    int R = wc * 96 + ni * 16 + m;
                    b[ni] = *(const bf16x8*)&Bs[R * 64 + (((s * 4 + qd) ^ (R & 7)) * 8)];
                }
#pragma unroll
                for (int mi = 0; mi < 2; ++mi) {
                    int R = wr * 32 + mi * 16 + m;
                    a[mi] = *(const bf16x8*)&As[R * 64 + (((s * 4 + qd) ^ (R & 7)) * 8)];
                }
                // swapped: D[row=out-dim local qd*4+rr][col=token local m]
#pragma unroll
                for (int mi = 0; mi < 2; ++mi)
#pragma unroll
                    for (int ni = 0; ni < 6; ++ni)
                        acc[mi][ni] = __builtin_amdgcn_mfma_f32_16x16x32_bf16(b[ni], a[mi], acc[mi][ni], 0, 0, 0);
            }
        }

        // epilogue: Q,K -> QKs[t][0..127]; V -> VT[d][t]
#pragma unroll
        for (int mi = 0; mi < 2; ++mi) {
            int t = wr * 32 + mi * 16 + m;
#pragma unroll
            for (int ni = 0; ni < 6; ++ni) {
                int cn = wc * 96 + ni * 16;
                float4 bb = *(const float4*)&biash[h * 192 + cn + qd * 4];
                if (cn < 128) {
                    *(uint2*)&QKs[t * 136 + cn + qd * 4] =
                        pack4(acc[mi][ni][0] + bb.x, acc[mi][ni][1] + bb.y,
                              acc[mi][ni][2] + bb.z, acc[mi][ni][3] + bb.w);
                } else {
                    int d0 = cn - 128 + qd * 4;
                    VT[(d0 + 0) * 72 + t] = f2b(acc[mi][ni][0] + bb.x);
                    VT[(d0 + 1) * 72 + t] = f2b(acc[mi][ni][1] + bb.y);
                    VT[(d0 + 2) * 72 + t] = f2b(acc[mi][ni][2] + bb.z);
                    VT[(d0 + 3) * 72 + t] = f2b(acc[mi][ni][3] + bb.w);
                }
            }
        }
        __syncthreads();

        // ---- attention: wave handles S rows q0..q0+15 ----
        const int q0 = wid * 16;
        f32x4 sa[4];
#pragma unroll
        for (int ni = 0; ni < 4; ++ni) sa[ni] = (f32x4){0.f, 0.f, 0.f, 0.f};
#pragma unroll
        for (int s = 0; s < 2; ++s) {
            bf16x8 qf = *(const bf16x8*)&QKs[(q0 + m) * 136 + s * 32 + qd * 8];
#pragma unroll
            for (int ni = 0; ni < 4; ++ni) {
                bf16x8 kf = *(const bf16x8*)&QKs[(ni * 16 + m) * 136 + 64 + s * 32 + qd * 8];
                sa[ni] = __builtin_amdgcn_mfma_f32_16x16x32_bf16(qf, kf, sa[ni], 0, 0, 0);
            }
        }
        const float c1 = 0.125f * 1.4426950408889634f;
#pragma unroll
        for (int rr = 0; rr < 4; ++rr) {
            float mx = -3.4e38f;
#pragma unroll
            for (int ni = 0; ni < 4; ++ni) mx = fmaxf(mx, sa[ni][rr]);
            mx = fmaxf(mx, __shfl_xor(mx, 1, 64));
            mx = fmaxf(mx, __shfl_xor(mx, 2, 64));
            mx = fmaxf(mx, __shfl_xor(mx, 4, 64));
            mx = fmaxf(mx, __shfl_xor(mx, 8, 64));
            float sum = 0.f;
#pragma unroll
            for (int ni = 0; ni < 4; ++ni) {
                float p = exp2f((sa[ni][rr] - mx) * c1);
                sa[ni][rr] = p;
                sum += p;
            }
            sum += __shfl_xor(sum, 1, 64);
            sum += __shfl_xor(sum, 2, 64);
            sum += __shfl_xor(sum, 4, 64);
            sum += __shfl_xor(sum, 8, 64);
            float inv = 1.f / sum;
            int r = qd * 4 + rr;
#pragma unroll
            for (int ni = 0; ni < 4; ++ni)
                Pw[r * 136 + ni * 16 + m] = f2b(sa[ni][rr] * inv);
        }

        f32x4 oa[4];
#pragma unroll
        for (int ni = 0; ni < 4; ++ni) oa[ni] = (f32x4){0.f, 0.f, 0.f, 0.f};
#pragma unroll
        for (int s = 0; s < 2; ++s) {
            bf16x8 pf = *(const bf16x8*)&Pw[m * 136 + s * 32 + qd * 8];
#pragma unroll
            for (int ni = 0; ni < 4; ++ni) {
                bf16x8 vf = *(const bf16x8*)&VT[(ni * 16 + m) * 72 + s * 32 + qd * 8];
                // swapped: D[row=d local][col=q-token local]
                oa[ni] = __builtin_amdgcn_mfma_f32_16x16x32_bf16(vf, pf, oa[ni], 0, 0, 0);
            }
        }
        u16* dst = ows + (size_t)(rowBase + q0 + m) * 512 + h * 64;
#pragma unroll
        for (int ni = 0; ni < 4; ++ni)
            *(uint2*)&dst[ni * 16 + qd * 4] =
                pack4(oa[ni][0], oa[ni][1], oa[ni][2], oa[ni][3]);
        // next head's staging barrier (loop top) protects Pw/QKs/VT reuse
    }
}

// ---------------- proj GEMM: M=32768 N=512 K=512, BK=64, swapped epilogue ----------------
__global__ __launch_bounds__(256) void proj_gemm(const u16* __restrict__ ows,
        const u16* __restrict__ woT, const float* __restrict__ bo,
        const float* __restrict__ x, float* __restrict__ out) {
    __shared__ u16 As[128 * 64];
    __shared__ u16 Bs[128 * 64];
    const int tid = threadIdx.x;
    const int lane = tid & 63, wid = tid >> 6;
    const int wr = wid >> 1, wc = wid & 1;
    const int m = lane & 15, qd = lane >> 4;
    const int rowBase = blockIdx.y * 128;
    const int colBase = blockIdx.x * 128;
    const int c8 = (lane & 7) ^ (lane >> 3);

    f32x4 acc[4][4];
#pragma unroll
    for (int i = 0; i < 4; ++i)
#pragma unroll
        for (int j = 0; j < 4; ++j) acc[i][j] = (f32x4){0.f, 0.f, 0.f, 0.f};

    for (int kt = 0; kt < 8; ++kt) {
        const int k0 = kt * 64;
        __syncthreads();
#pragma unroll
        for (int j = 0; j < 4; ++j) {
            int q = (j * 4 + wid) * 64 + lane;
            int r = (j * 4 + wid) * 8 + (lane >> 3);
            gll16(ows + (size_t)(rowBase + r) * 512 + k0 + c8 * 8, &As[q * 8]);
            gll16(woT + (size_t)(colBase + r) * 512 + k0 + c8 * 8, &Bs[q * 8]);
        }
        __syncthreads();
#pragma unroll
        for (int s = 0; s < 2; ++s) {
            bf16x8 a[4], b[4];
#pragma unroll
            for (int ni = 0; ni < 4; ++ni) {
                int R = wc * 64 + ni * 16 + m;
                b[ni] = *(const bf16x8*)&Bs[R * 64 + (((s * 4 + qd) ^ (R & 7)) * 8)];
            }
#pragma unroll
            for (int mi = 0; mi < 4; ++mi) {
                int R = wr * 64 + mi * 16 + m;
                a[mi] = *(const bf16x8*)&As[R * 64 + (((s * 4 + qd) ^ (R & 7)) * 8)];
            }
            // swapped: D[row=col-dim local][col=token local]
#pragma unroll
            for (int mi = 0; mi < 4; ++mi)
#pragma unroll
                for (int ni = 0; ni < 4; ++ni)
                    acc[mi][ni] = __builtin_amdgcn_mfma_f32_16x16x32_bf16(b[ni], a[mi], acc[mi][ni], 0, 0, 0);
        }
    }

#pragma unroll
    for (int mi = 0; mi < 4; ++mi) {
        int row = rowBase + wr * 64 + mi * 16 + m;    // win*64 + t
        int win = row >> 6, t = row & 63;
        int b_ = win >> 6, wh = (win >> 3) & 7, ww_ = win & 7;
        int ti = t >> 3, tj = t & 7;
        int hh = (wh * 8 + ti + 4) & 63;
        int www = (ww_ * 8 + tj + 4) & 63;
        size_t tok = (size_t)b_ * 4096 + hh * 64 + www;
#pragma unroll
        for (int ni = 0; ni < 4; ++ni) {
            int col0 = colBase + wc * 64 + ni * 16 + qd * 4;
            float4 xv = *(const float4*)&x[tok * 512 + col0];
            float4 bv = *(const float4*)&bo[col0];
            float4 o;
            o.x = acc[mi][ni][0] + bv.x + xv.x;
            o.y = acc[mi][ni][1] + bv.y + xv.y;
            o.z = acc[mi][ni][2] + bv.z + xv.z;
            o.w = acc[mi][ni][3] + bv.w + xv.w;
            *(float4*)&out[tok * 512 + col0] = o;
        }
    }
}

extern "C" void kernel_launch(void* const* d_in, const int* in_sizes, int n_in,
                              void* d_out, int out_size, void* d_ws, size_t ws_size,
                              hipStream_t stream) {
    const float* x  = (const float*)d_in[0];
    const float* wq = (const float*)d_in[1];
    const float* bq = (const float*)d_in[2];
    const float* wk = (const float*)d_in[3];
    const float* bk = (const float*)d_in[4];
    const float* wv = (const float*)d_in[5];
    const float* bv = (const float*)d_in[6];
    const float* wo = (const float*)d_in[7];
    const float* bo = (const float*)d_in[8];
    float* out = (float*)d_out;
    char* ws = (char*)d_ws;

    u16*   wqkvh = (u16*)ws;                               // 1536*512*2
    u16*   woT   = (u16*)(ws + 1572864);                   // 512*512*2
    float* biash = (float*)(ws + 1572864 + 524288);        // 1536*4
    size_t off = 2103296;
    u16* xw  = (u16*)(ws + off);                           // 32768*512 u16 = 32 MiB
    u16* ows = xw + (size_t)16777216;                      // 32768*512 u16 = 32 MiB

    const int prepN = 512 * 1536 + 512 * 512 + 1536;
    prep_kernel<<<dim3((prepN + 255) / 256), dim3(256), 0, stream>>>(
        wq, wk, wv, wo, bq, bk, bv, wqkvh, woT, biash);
    pre_kernel<<<dim3(8192), dim3(256), 0, stream>>>(x, xw);
    fused_qkv_attn<<<dim3(512), dim3(256), 0, stream>>>(xw, wqkvh, biash, ows);
    proj_gemm<<<dim3(4, 256), dim3(256), 0, stream>>>(ows, woT, bo, x, out);
}